// Round 6
// baseline (121.616 us; speedup 1.0000x reference)
//
#include <hip/hip_runtime.h>

// Bilinear table interpolation, TF _interpolate_bilinear semantics.
// R6: depth probe. Same packed-bf16 row-pair table as R5 (4.19 MB, L2-resident,
// ONE 8B gather/point). 16 points/thread (was 8): doubles per-thread outstanding
// misses to discriminate TCP miss-RATE wall (neutral) vs miss-DEPTH wall (-20%).
// Table: P[y][x] = bf16(grid[y][x]) | bf16(grid[y+1][x])<<16.

#define GRID_H 1024
#define GRID_W 1024
#define PTS 16

typedef float floatx4 __attribute__((ext_vector_type(4)));
typedef float floatx2 __attribute__((ext_vector_type(2)));
typedef unsigned int uintx2 __attribute__((ext_vector_type(2)));
typedef unsigned int uintx4 __attribute__((ext_vector_type(4)));

__device__ __forceinline__ unsigned int f32_to_bf16_rne(float f) {
    unsigned int u = __builtin_bit_cast(unsigned int, f);
    u += 0x7fffu + ((u >> 16) & 1u);   // round-to-nearest-even
    return u >> 16;
}

// ---------- prep: build packed row-pair table ----------
__global__ __launch_bounds__(256) void buildPair_kernel(
    const float* __restrict__ grid,      // H*W
    unsigned int* __restrict__ pair,     // (H-1)*W entries
    int n_groups)                        // (H-1)*W/4
{
    int g = blockIdx.x * blockDim.x + threadIdx.x;
    if (g >= n_groups) return;
    int idx = g * 4;
    int y = idx >> 10;                   // / GRID_W
    int x = idx & (GRID_W - 1);          // multiple of 4
    const floatx4* r0 = (const floatx4*)(grid + (y << 10) + x);
    const floatx4* r1 = (const floatx4*)(grid + ((y + 1) << 10) + x);
    floatx4 t = *r0;
    floatx4 b = *r1;
    uintx4 o;
    o.x = f32_to_bf16_rne(t.x) | (f32_to_bf16_rne(b.x) << 16);
    o.y = f32_to_bf16_rne(t.y) | (f32_to_bf16_rne(b.y) << 16);
    o.z = f32_to_bf16_rne(t.z) | (f32_to_bf16_rne(b.z) << 16);
    o.w = f32_to_bf16_rne(t.w) | (f32_to_bf16_rne(b.w) << 16);
    *(uintx4*)(pair + idx) = o;
}

// ---------- main: 16 points/thread, ONE 8B gather per point ----------
__global__ __launch_bounds__(256) void interpPair_kernel(
    const float* __restrict__ in,            // N*2 floats (x, v)
    const unsigned int* __restrict__ pair,   // packed table
    const float* __restrict__ bounds,        // [x_lo,x_hi,v_lo,v_hi]
    float* __restrict__ out,                 // N floats
    int n_pts)
{
    const int H = GRID_H, W = GRID_W;
    const float x_lo = bounds[0];
    const float x_hi = bounds[1];
    const float v_lo = bounds[2];
    const float v_hi = bounds[3];
    const float sy = (float)(H - 1) / (x_hi - x_lo);
    const float sx = (float)(W - 1) / (v_hi - v_lo);

    const int t = blockIdx.x * blockDim.x + threadIdx.x;
    const int base = t * PTS;
    if (base >= n_pts) return;

    float xs[PTS], vs[PTS], res[PTS];

    if (base + PTS - 1 < n_pts) {
        const floatx4* in4 = (const floatx4*)in;
#pragma unroll
        for (int q = 0; q < PTS / 2; ++q) {
            floatx4 p = __builtin_nontemporal_load(&in4[(PTS / 2) * t + q]);
            xs[2 * q + 0] = p.x; vs[2 * q + 0] = p.y;
            xs[2 * q + 1] = p.z; vs[2 * q + 1] = p.w;
        }
    } else {
#pragma unroll
        for (int k = 0; k < PTS; ++k) {
            int p = base + k < n_pts ? base + k : n_pts - 1;
            xs[k] = in[2 * p + 0];
            vs[k] = in[2 * p + 1];
        }
    }

    float ays[PTS], axs[PTS];
    int qidx[PTS];
#pragma unroll
    for (int k = 0; k < PTS; ++k) {
        float qy = (xs[k] - x_lo) * sy;
        float qx = (vs[k] - v_lo) * sx;
        float fy = fminf(fmaxf(floorf(qy), 0.0f), (float)(H - 2));
        float fx = fminf(fmaxf(floorf(qx), 0.0f), (float)(W - 2));
        ays[k] = fminf(fmaxf(qy - fy, 0.0f), 1.0f);
        axs[k] = fminf(fmaxf(qx - fx, 0.0f), 1.0f);
        qidx[k] = ((int)fy << 10) + (int)fx;   // y0*W + x0
    }

    // Batch all 16 gathers (8B each; entries x0, x0+1) before first use.
    uintx2 c[PTS];
#pragma unroll
    for (int k = 0; k < PTS; ++k)
        c[k] = *(const uintx2*)(pair + qidx[k]);

#pragma unroll
    for (int k = 0; k < PTS; ++k) {
        float tl = __builtin_bit_cast(float, c[k].x << 16);
        float bl = __builtin_bit_cast(float, c[k].x & 0xffff0000u);
        float tr = __builtin_bit_cast(float, c[k].y << 16);
        float br = __builtin_bit_cast(float, c[k].y & 0xffff0000u);
        float top = tl + (tr - tl) * axs[k];
        float bot = bl + (br - bl) * axs[k];
        res[k] = top + (bot - top) * ays[k];
    }

    if (base + PTS - 1 < n_pts) {
        floatx4* out4 = (floatx4*)out;
#pragma unroll
        for (int q = 0; q < PTS / 4; ++q) {
            floatx4 o;
            o.x = res[4 * q + 0]; o.y = res[4 * q + 1];
            o.z = res[4 * q + 2]; o.w = res[4 * q + 3];
            __builtin_nontemporal_store(o, &out4[(PTS / 4) * t + q]);
        }
    } else {
#pragma unroll
        for (int k = 0; k < PTS; ++k)
            if (base + k < n_pts) out[base + k] = res[k];
    }
}

// ---------- fallback (R3 structure) if d_ws is too small ----------
__global__ __launch_bounds__(256) void interpRaw_kernel(
    const float* __restrict__ in, const float* __restrict__ grid,
    const float* __restrict__ bounds, float* __restrict__ out, int n_pts)
{
    const int H = GRID_H, W = GRID_W;
    const float x_lo = bounds[0], x_hi = bounds[1];
    const float v_lo = bounds[2], v_hi = bounds[3];
    const float sy = (float)(H - 1) / (x_hi - x_lo);
    const float sx = (float)(W - 1) / (v_hi - v_lo);
    const int t = blockIdx.x * blockDim.x + threadIdx.x;
    const int base = t * 4;
    if (base >= n_pts) return;
    float xs[4], vs[4], res[4];
#pragma unroll
    for (int k = 0; k < 4; ++k) {
        int p = base + k < n_pts ? base + k : n_pts - 1;
        xs[k] = in[2 * p + 0];
        vs[k] = in[2 * p + 1];
    }
    float ays[4], axs[4];
    const floatx2 *gt[4], *gb[4];
#pragma unroll
    for (int k = 0; k < 4; ++k) {
        float qy = (xs[k] - x_lo) * sy;
        float qx = (vs[k] - v_lo) * sx;
        float fy = fminf(fmaxf(floorf(qy), 0.0f), (float)(H - 2));
        float fx = fminf(fmaxf(floorf(qx), 0.0f), (float)(W - 2));
        ays[k] = fminf(fmaxf(qy - fy, 0.0f), 1.0f);
        axs[k] = fminf(fmaxf(qx - fx, 0.0f), 1.0f);
        const float* g = grid + ((int)fy << 10) + (int)fx;
        gt[k] = (const floatx2*)g;
        gb[k] = (const floatx2*)(g + W);
    }
    floatx2 t2[4], b2[4];
#pragma unroll
    for (int k = 0; k < 4; ++k) { t2[k] = *gt[k]; b2[k] = *gb[k]; }
#pragma unroll
    for (int k = 0; k < 4; ++k) {
        float top = t2[k].x + (t2[k].y - t2[k].x) * axs[k];
        float bot = b2[k].x + (b2[k].y - b2[k].x) * axs[k];
        res[k] = top + (bot - top) * ays[k];
    }
#pragma unroll
    for (int k = 0; k < 4; ++k)
        if (base + k < n_pts) out[base + k] = res[k];
}

extern "C" void kernel_launch(void* const* d_in, const int* in_sizes, int n_in,
                              void* d_out, int out_size, void* d_ws, size_t ws_size,
                              hipStream_t stream) {
    const float* in     = (const float*)d_in[0];   // (N, 2) fp32
    const float* grid   = (const float*)d_in[1];   // (H, W) fp32
    const float* bounds = (const float*)d_in[2];   // (2, 2) fp32
    float* out = (float*)d_out;                    // N fp32

    const int n_pts = in_sizes[0] / 2;
    const int n_entries = (GRID_H - 1) * GRID_W;           // 1023*1024
    const size_t pair_bytes = (size_t)n_entries * 4;       // 4.19 MB

    if (ws_size >= pair_bytes) {
        unsigned int* pair = (unsigned int*)d_ws;
        const int n_groups = n_entries / 4;                // W % 4 == 0
        buildPair_kernel<<<(n_groups + 255) / 256, 256, 0, stream>>>(grid, pair, n_groups);
        const int n_threads = (n_pts + PTS - 1) / PTS;
        interpPair_kernel<<<(n_threads + 255) / 256, 256, 0, stream>>>(
            in, pair, bounds, out, n_pts);
    } else {
        const int n_threads = (n_pts + 3) / 4;
        interpRaw_kernel<<<(n_threads + 255) / 256, 256, 0, stream>>>(
            in, grid, bounds, out, n_pts);
    }
}

// Round 7
// 115.384 us; speedup vs baseline: 1.0540x; 1.0540x over previous
//
#include <hip/hip_runtime.h>

// Bilinear table interpolation, TF _interpolate_bilinear semantics.
// R7 = R5 restored (best config) + gathers issued as addresses are computed.
// Packed bf16 row-pair table: P[y][x] = bf16(grid[y][x]) | bf16(grid[y+1][x])<<16,
// 4.19 MB -> per-XCD-L2 resident. ONE 8B gather/point yields all 4 corners.
// PTS=8 is the unique full-occupancy config: N/8 = 524288 threads = 256 CU x 2048.
// (R6 showed 16 pts/thread halves occupancy and loses; R4 showed fp32 quad table
// thrashes L2 and loses.)

#define GRID_H 1024
#define GRID_W 1024
#define PTS 8

typedef float floatx4 __attribute__((ext_vector_type(4)));
typedef float floatx2 __attribute__((ext_vector_type(2)));
typedef unsigned int uintx2 __attribute__((ext_vector_type(2)));
typedef unsigned int uintx4 __attribute__((ext_vector_type(4)));

__device__ __forceinline__ unsigned int f32_to_bf16_rne(float f) {
    unsigned int u = __builtin_bit_cast(unsigned int, f);
    u += 0x7fffu + ((u >> 16) & 1u);   // round-to-nearest-even
    return u >> 16;
}

// ---------- prep: build packed row-pair table ----------
__global__ __launch_bounds__(256) void buildPair_kernel(
    const float* __restrict__ grid,      // H*W
    unsigned int* __restrict__ pair,     // (H-1)*W entries
    int n_groups)                        // (H-1)*W/4
{
    int g = blockIdx.x * blockDim.x + threadIdx.x;
    if (g >= n_groups) return;
    int idx = g * 4;
    int y = idx >> 10;                   // / GRID_W
    int x = idx & (GRID_W - 1);          // multiple of 4
    const floatx4* r0 = (const floatx4*)(grid + (y << 10) + x);
    const floatx4* r1 = (const floatx4*)(grid + ((y + 1) << 10) + x);
    floatx4 t = *r0;
    floatx4 b = *r1;
    uintx4 o;
    o.x = f32_to_bf16_rne(t.x) | (f32_to_bf16_rne(b.x) << 16);
    o.y = f32_to_bf16_rne(t.y) | (f32_to_bf16_rne(b.y) << 16);
    o.z = f32_to_bf16_rne(t.z) | (f32_to_bf16_rne(b.z) << 16);
    o.w = f32_to_bf16_rne(t.w) | (f32_to_bf16_rne(b.w) << 16);
    *(uintx4*)(pair + idx) = o;
}

// ---------- main: 8 points/thread, ONE 8B gather per point ----------
__global__ __launch_bounds__(256) void interpPair_kernel(
    const float* __restrict__ in,            // N*2 floats (x, v)
    const unsigned int* __restrict__ pair,   // packed table
    const float* __restrict__ bounds,        // [x_lo,x_hi,v_lo,v_hi]
    float* __restrict__ out,                 // N floats
    int n_pts)
{
    const int H = GRID_H, W = GRID_W;
    const float x_lo = bounds[0];
    const float x_hi = bounds[1];
    const float v_lo = bounds[2];
    const float v_hi = bounds[3];
    const float sy = (float)(H - 1) / (x_hi - x_lo);
    const float sx = (float)(W - 1) / (v_hi - v_lo);

    const int t = blockIdx.x * blockDim.x + threadIdx.x;
    const int base = t * PTS;
    if (base >= n_pts) return;

    float xs[PTS], vs[PTS], res[PTS];

    if (base + PTS - 1 < n_pts) {
        const floatx4* in4 = (const floatx4*)in;
#pragma unroll
        for (int q = 0; q < PTS / 2; ++q) {
            floatx4 p = __builtin_nontemporal_load(&in4[(PTS / 2) * t + q]);
            xs[2 * q + 0] = p.x; vs[2 * q + 0] = p.y;
            xs[2 * q + 1] = p.z; vs[2 * q + 1] = p.w;
        }
    } else {
#pragma unroll
        for (int k = 0; k < PTS; ++k) {
            int p = base + k < n_pts ? base + k : n_pts - 1;
            xs[k] = in[2 * p + 0];
            vs[k] = in[2 * p + 1];
        }
    }

    // Compute each address and issue its gather immediately; consume later.
    float ays[PTS], axs[PTS];
    uintx2 c[PTS];
#pragma unroll
    for (int k = 0; k < PTS; ++k) {
        float qy = (xs[k] - x_lo) * sy;
        float qx = (vs[k] - v_lo) * sx;
        float fy = fminf(fmaxf(floorf(qy), 0.0f), (float)(H - 2));
        float fx = fminf(fmaxf(floorf(qx), 0.0f), (float)(W - 2));
        ays[k] = fminf(fmaxf(qy - fy, 0.0f), 1.0f);
        axs[k] = fminf(fmaxf(qx - fx, 0.0f), 1.0f);
        int qidx = ((int)fy << 10) + (int)fx;   // y0*W + x0
        c[k] = *(const uintx2*)(pair + qidx);
    }

#pragma unroll
    for (int k = 0; k < PTS; ++k) {
        float tl = __builtin_bit_cast(float, c[k].x << 16);
        float bl = __builtin_bit_cast(float, c[k].x & 0xffff0000u);
        float tr = __builtin_bit_cast(float, c[k].y << 16);
        float br = __builtin_bit_cast(float, c[k].y & 0xffff0000u);
        float top = tl + (tr - tl) * axs[k];
        float bot = bl + (br - bl) * axs[k];
        res[k] = top + (bot - top) * ays[k];
    }

    if (base + PTS - 1 < n_pts) {
        floatx4* out4 = (floatx4*)out;
#pragma unroll
        for (int q = 0; q < PTS / 4; ++q) {
            floatx4 o;
            o.x = res[4 * q + 0]; o.y = res[4 * q + 1];
            o.z = res[4 * q + 2]; o.w = res[4 * q + 3];
            __builtin_nontemporal_store(o, &out4[(PTS / 4) * t + q]);
        }
    } else {
#pragma unroll
        for (int k = 0; k < PTS; ++k)
            if (base + k < n_pts) out[base + k] = res[k];
    }
}

// ---------- fallback (R3 structure) if d_ws is too small ----------
__global__ __launch_bounds__(256) void interpRaw_kernel(
    const float* __restrict__ in, const float* __restrict__ grid,
    const float* __restrict__ bounds, float* __restrict__ out, int n_pts)
{
    const int H = GRID_H, W = GRID_W;
    const float x_lo = bounds[0], x_hi = bounds[1];
    const float v_lo = bounds[2], v_hi = bounds[3];
    const float sy = (float)(H - 1) / (x_hi - x_lo);
    const float sx = (float)(W - 1) / (v_hi - v_lo);
    const int t = blockIdx.x * blockDim.x + threadIdx.x;
    const int base = t * 4;
    if (base >= n_pts) return;
    float xs[4], vs[4], res[4];
#pragma unroll
    for (int k = 0; k < 4; ++k) {
        int p = base + k < n_pts ? base + k : n_pts - 1;
        xs[k] = in[2 * p + 0];
        vs[k] = in[2 * p + 1];
    }
    float ays[4], axs[4];
    const floatx2 *gt[4], *gb[4];
#pragma unroll
    for (int k = 0; k < 4; ++k) {
        float qy = (xs[k] - x_lo) * sy;
        float qx = (vs[k] - v_lo) * sx;
        float fy = fminf(fmaxf(floorf(qy), 0.0f), (float)(H - 2));
        float fx = fminf(fmaxf(floorf(qx), 0.0f), (float)(W - 2));
        ays[k] = fminf(fmaxf(qy - fy, 0.0f), 1.0f);
        axs[k] = fminf(fmaxf(qx - fx, 0.0f), 1.0f);
        const float* g = grid + ((int)fy << 10) + (int)fx;
        gt[k] = (const floatx2*)g;
        gb[k] = (const floatx2*)(g + W);
    }
    floatx2 t2[4], b2[4];
#pragma unroll
    for (int k = 0; k < 4; ++k) { t2[k] = *gt[k]; b2[k] = *gb[k]; }
#pragma unroll
    for (int k = 0; k < 4; ++k) {
        float top = t2[k].x + (t2[k].y - t2[k].x) * axs[k];
        float bot = b2[k].x + (b2[k].y - b2[k].x) * axs[k];
        res[k] = top + (bot - top) * ays[k];
    }
#pragma unroll
    for (int k = 0; k < 4; ++k)
        if (base + k < n_pts) out[base + k] = res[k];
}

extern "C" void kernel_launch(void* const* d_in, const int* in_sizes, int n_in,
                              void* d_out, int out_size, void* d_ws, size_t ws_size,
                              hipStream_t stream) {
    const float* in     = (const float*)d_in[0];   // (N, 2) fp32
    const float* grid   = (const float*)d_in[1];   // (H, W) fp32
    const float* bounds = (const float*)d_in[2];   // (2, 2) fp32
    float* out = (float*)d_out;                    // N fp32

    const int n_pts = in_sizes[0] / 2;
    const int n_entries = (GRID_H - 1) * GRID_W;           // 1023*1024
    const size_t pair_bytes = (size_t)n_entries * 4;       // 4.19 MB

    if (ws_size >= pair_bytes) {
        unsigned int* pair = (unsigned int*)d_ws;
        const int n_groups = n_entries / 4;                // W % 4 == 0
        buildPair_kernel<<<(n_groups + 255) / 256, 256, 0, stream>>>(grid, pair, n_groups);
        const int n_threads = (n_pts + PTS - 1) / PTS;
        interpPair_kernel<<<(n_threads + 255) / 256, 256, 0, stream>>>(
            in, pair, bounds, out, n_pts);
    } else {
        const int n_threads = (n_pts + 3) / 4;
        interpRaw_kernel<<<(n_threads + 255) / 256, 256, 0, stream>>>(
            in, grid, bounds, out, n_pts);
    }
}